// Round 1
// baseline (488.703 us; speedup 1.0000x reference)
//
#include <hip/hip_runtime.h>

typedef __bf16 bf16_t;
typedef bf16_t bf16x8 __attribute__((ext_vector_type(8)));
typedef float f32x4 __attribute__((ext_vector_type(4)));

#define BATCH 16384
#define HID 256

// ---------- bf16 helpers (manual RNE, no header dependency) ----------
__device__ __forceinline__ ushort f2b(float f) {
  union { float f; unsigned u; } v; v.f = f;
  unsigned u = v.u;
  unsigned r = (u + 0x7fffu + ((u >> 16) & 1u)) >> 16;
  return (ushort)r;
}
__device__ __forceinline__ float b2f(ushort u) {
  union { unsigned u; float f; } v; v.u = ((unsigned)u) << 16; return v.f;
}
__device__ __forceinline__ void loadbf4(const ushort* __restrict__ p, float* o) {
  uint2 q = *(const uint2*)p;
  o[0] = b2f((ushort)(q.x & 0xffffu));
  o[1] = b2f((ushort)(q.x >> 16));
  o[2] = b2f((ushort)(q.y & 0xffffu));
  o[3] = b2f((ushort)(q.y >> 16));
}
__device__ __forceinline__ uint2 packbf4(const float* v) {
  uint2 q;
  q.x = (unsigned)f2b(v[0]) | ((unsigned)f2b(v[1]) << 16);
  q.y = (unsigned)f2b(v[2]) | ((unsigned)f2b(v[3]) << 16);
  return q;
}

// ---------- convert fp32 -> bf16 (x and h in one launch) ----------
__global__ __launch_bounds__(256)
void f2b2_kernel(const float* __restrict__ a, const float* __restrict__ b,
                 ushort* __restrict__ oa, ushort* __restrict__ ob) {
  int bid = blockIdx.x;
  const float* in = (bid < 4096) ? a : b;
  ushort* out     = (bid < 4096) ? oa : ob;
  int t = (bid & 4095) * 256 + threadIdx.x;     // 1,048,576 threads per tensor, 4 elems each
  float4 v = *(const float4*)(in + (size_t)t * 4);
  float q[4] = {v.x, v.y, v.z, v.w};
  *(uint2*)(out + (size_t)t * 4) = packbf4(q);
}

// ---------- build transposed bf16 weights: Wt[ksel*256+d][h] = W[ksel][h][d] (L and R in one launch) ----------
__global__ __launch_bounds__(256)
void wt2_kernel(const float* __restrict__ L, const float* __restrict__ R,
                ushort* __restrict__ Lt, ushort* __restrict__ Rt) {
  int bid = blockIdx.x;
  const float* W = (bid < 1024) ? L : R;
  ushort* Wt     = (bid < 1024) ? Lt : Rt;
  int idx = (bid & 1023) * 256 + threadIdx.x;    // 262,144 per matrix set
  int c = idx >> 8, hh = idx & 255;
  int ks = c >> 8, d = c & 255;
  Wt[idx] = f2b(W[ks * 65536 + hh * 256 + d]);
}

// ---------- bf16 MFMA GEMM: P[M,N] = A[M,256] @ W  (W given pre-transposed Wt[N][256]) ----------
// 128x128 tile, BK=64 double-buffered 2-phase pipeline, global_load_lds(16B) staging,
// XOR granule swizzle (source-side + read-side, same involution), XCD-aware block swizzle.
// 4 waves in 2x2, each wave 4x4 of 16x16x32 MFMA.
__global__ __launch_bounds__(256, 2)
void gemm_kernel(const ushort* __restrict__ A, const ushort* __restrict__ Wt,
                 ushort* __restrict__ P, int N) {
  // linear LDS (global_load_lds requires contiguous dest): [2 bufs][128 rows][64 bf16]
  __shared__ __align__(16) ushort As[2][128 * 64];
  __shared__ __align__(16) ushort Bs[2][128 * 64];

  const int tid  = threadIdx.x;
  const int lane = tid & 63;
  const int wave = tid >> 6;

  // XCD-aware bijective swizzle: nwg is 1024 or 512, both % 8 == 0.
  const int nwg = gridDim.x;
  const int q   = nwg >> 3;
  const int bid = blockIdx.x;
  const int id2 = (bid & 7) * q + (bid >> 3);
  const int nx  = N >> 7;                 // 8 or 4 column-tiles
  const int lnx = (nx == 8) ? 3 : 2;
  const int cn  = id2 & (nx - 1);
  const int cm  = id2 >> lnx;
  const int bm  = cm * 128;
  const int bn  = cn * 128;

  const int wm   = (wave >> 1) * 64;
  const int wn   = (wave & 1) * 64;
  const int row  = lane & 15;
  const int quad = lane >> 4;

  // staging geometry: 16 chunks of 1KB (8 rows x 64 bf16); wave w owns chunks w*4..w*4+3
  const int r_s = lane >> 3;              // row within 8-row chunk
  const int g_s = lane & 7;               // 16B granule within row
  const int gsw = g_s ^ r_s;              // inverse-swizzled source granule (r&7 == r_s)

  f32x4 acc[4][4] = {};

#define STAGE(buf, t)                                                              \
  {                                                                                \
    const int k0 = (t) * 64;                                                       \
    for (int i = 0; i < 4; ++i) {                                                  \
      const int ci = wave * 4 + i;                                                 \
      const int r  = ci * 8 + r_s;                                                 \
      const ushort* srcA = A  + (size_t)(bm + r) * 256 + k0 + gsw * 8;             \
      const ushort* srcB = Wt + (size_t)(bn + r) * 256 + k0 + gsw * 8;             \
      __builtin_amdgcn_global_load_lds(                                            \
          (const __attribute__((address_space(1))) void*)srcA,                     \
          (__attribute__((address_space(3))) void*)&As[buf][ci * 512], 16, 0, 0);  \
      __builtin_amdgcn_global_load_lds(                                            \
          (const __attribute__((address_space(1))) void*)srcB,                     \
          (__attribute__((address_space(3))) void*)&Bs[buf][ci * 512], 16, 0, 0);  \
    }                                                                              \
  }

#define COMPUTE(buf)                                                               \
  {                                                                                \
    bf16x8 af[2][4], bf[2][4];                                                     \
    for (int kk = 0; kk < 2; ++kk)                                                 \
      for (int t = 0; t < 4; ++t) {                                                \
        const int ar = wm + t * 16 + row;                                          \
        const int ga = (kk * 4 + quad) ^ (ar & 7);                                 \
        af[kk][t] = *(const bf16x8*)&As[buf][ar * 64 + ga * 8];                    \
        const int br = wn + t * 16 + row;                                          \
        const int gb = (kk * 4 + quad) ^ (br & 7);                                 \
        bf[kk][t] = *(const bf16x8*)&Bs[buf][br * 64 + gb * 8];                    \
      }                                                                            \
    for (int kk = 0; kk < 2; ++kk)                                                 \
      for (int ti = 0; ti < 4; ++ti)                                               \
        for (int tj = 0; tj < 4; ++tj)                                             \
          acc[ti][tj] = __builtin_amdgcn_mfma_f32_16x16x32_bf16(                   \
              af[kk][ti], bf[kk][tj], acc[ti][tj], 0, 0, 0);                       \
  }

  STAGE(0, 0);
  __syncthreads();                 // drains vmcnt: buf0 ready
  COMPUTE(0);
  STAGE(1, 1);
  // NOTE: STAGE(next) issued before barrier so HBM/L2 latency overlaps MFMA of cur
  __syncthreads();
  COMPUTE(1);
  STAGE(0, 2);
  __syncthreads();
  COMPUTE(0);
  STAGE(1, 3);
  __syncthreads();
  COMPUTE(1);
#undef STAGE
#undef COMPUTE

  // epilogue: D[m=quad*4+r][n=lane&15], store bf16
  for (int ti = 0; ti < 4; ++ti)
    for (int tj = 0; tj < 4; ++tj)
      for (int r2 = 0; r2 < 4; ++r2) {
        int gm = bm + wm + ti * 16 + quad * 4 + r2;
        int gn = bn + wn + tj * 16 + row;
        P[(size_t)gm * N + gn] = f2b(acc[ti][tj][r2]);
      }
}

// ---------- sigmoid stage: z1 = sig(xL0+hR0+b0) -> slots 0,2 ; r = sig(xL1+hR1+b1) -> slot 1 ----------
__global__ __launch_bounds__(256)
void sig_kernel(const ushort* __restrict__ P0, const ushort* __restrict__ P2,
                const float* __restrict__ bias, float* __restrict__ gnode,
                ushort* __restrict__ z1b, ushort* __restrict__ rb) {
  int t = blockIdx.x * 256 + threadIdx.x;     // 1,048,576
  int b = t >> 6;
  int d0 = (t & 63) * 4;
  float xl[4], hr[4], z[4], r[4];
  // z1
  loadbf4(P0 + (size_t)b * 1024 + d0, xl);
  loadbf4(P2 + (size_t)b * 512 + d0, hr);
  float4 bb = *(const float4*)(bias + d0);
  float bbb[4] = {bb.x, bb.y, bb.z, bb.w};
  for (int i = 0; i < 4; ++i) z[i] = 1.0f / (1.0f + expf(-(xl[i] + hr[i] + bbb[i])));
  size_t g = (size_t)b * 2304 + d0;
  for (int i = 0; i < 4; ++i) { gnode[g + i] = z[i]; gnode[g + 512 + i] = z[i]; }
  *(uint2*)(z1b + (size_t)b * 256 + d0) = packbf4(z);
  // r
  loadbf4(P0 + (size_t)b * 1024 + 256 + d0, xl);
  loadbf4(P2 + (size_t)b * 512 + 256 + d0, hr);
  float4 b1 = *(const float4*)(bias + 256 + d0);
  float b1b[4] = {b1.x, b1.y, b1.z, b1.w};
  for (int i = 0; i < 4; ++i) r[i] = 1.0f / (1.0f + expf(-(xl[i] + hr[i] + b1b[i])));
  for (int i = 0; i < 4; ++i) gnode[g + 256 + i] = r[i];
  *(uint2*)(rb + (size_t)b * 256 + d0) = packbf4(r);
}

// ---------- mixture: cand = f(P1,P2)+b ; softmax over k ; out ; score partial-sums ----------
// mode 0: P1+P2+b   mode 1: 1-(P1+b)   mode 2: P1*P2+b
__global__ __launch_bounds__(256)
void mix_kernel(const ushort* __restrict__ P1, const ushort* __restrict__ P2,
                const float* __restrict__ bias, const float* __restrict__ Ws,
                float* __restrict__ gnode, ushort* __restrict__ actout,
                float* __restrict__ hnext, float* __restrict__ part, int mode) {
  const int tid  = threadIdx.x;
  const int wave = tid >> 6;
  const int lane = tid & 63;
  const int row  = blockIdx.x * 4 + wave;
  const int d0   = lane * 4;
  float c[4][4];
  float sp[4];
  float4 w4 = *(const float4*)(Ws + d0);
  float ws4[4] = {w4.x, w4.y, w4.z, w4.w};
  for (int k = 0; k < 4; ++k) {
    float p1[4];
    loadbf4(P1 + (size_t)row * 1024 + k * 256 + d0, p1);
    float4 bb = *(const float4*)(bias + k * 256 + d0);
    float bv[4] = {bb.x, bb.y, bb.z, bb.w};
    float v[4];
    if (mode == 0) {
      float p2[4];
      loadbf4(P2 + (size_t)row * 1024 + k * 256 + d0, p2);
      for (int i = 0; i < 4; ++i) v[i] = p1[i] + p2[i] + bv[i];
    } else if (mode == 1) {
      for (int i = 0; i < 4; ++i) v[i] = 1.0f - (p1[i] + bv[i]);
    } else {
      float p2[4];
      loadbf4(P2 + (size_t)row * 1024 + k * 256 + d0, p2);
      for (int i = 0; i < 4; ++i) v[i] = p1[i] * p2[i] + bv[i];
    }
    float s = 0.f;
    for (int i = 0; i < 4; ++i) { c[k][i] = v[i]; s += v[i] * ws4[i]; }
    sp[k] = s;
  }
  // butterfly reduce over 64 lanes (all lanes end with full row-score)
  for (int m = 1; m < 64; m <<= 1)
    for (int k = 0; k < 4; ++k) sp[k] += __shfl_xor(sp[k], m, 64);
  // softmax over k
  float mx = fmaxf(fmaxf(sp[0], sp[1]), fmaxf(sp[2], sp[3]));
  float e0 = expf(sp[0] - mx), e1 = expf(sp[1] - mx), e2 = expf(sp[2] - mx), e3 = expf(sp[3] - mx);
  float inv = 1.0f / (e0 + e1 + e2 + e3);
  float w0 = e0 * inv, w1 = e1 * inv, w2 = e2 * inv, w3 = e3 * inv;
  float o[4];
  for (int i = 0; i < 4; ++i) o[i] = w0 * c[0][i] + w1 * c[1][i] + w2 * c[2][i] + w3 * c[3][i];
  size_t g = (size_t)row * 2304 + d0;   // gnode already offset by slot*256; 4B-aligned only
  for (int i = 0; i < 4; ++i) gnode[g + i] = o[i];
  if (actout) *(uint2*)(actout + (size_t)row * 256 + d0) = packbf4(o);
  if (hnext) { float4 ov = {o[0], o[1], o[2], o[3]}; *(float4*)(hnext + (size_t)row * 256 + d0) = ov; }
  // per-block score partials (deterministic; no global atomics)
  __shared__ float sred[4][4];
  if (lane == 0) for (int k = 0; k < 4; ++k) sred[wave][k] = sp[k];
  __syncthreads();
  if (tid < 4)
    part[blockIdx.x * 4 + tid] = sred[0][tid] + sred[1][tid] + sred[2][tid] + sred[3][tid];
}

// ---------- finalize: reduce score partials, argmax + margin, G_structure ----------
__global__ __launch_bounds__(256)
void fin_kernel(const float* __restrict__ part, float* __restrict__ gs,
                float* __restrict__ margins) {
  __shared__ float red[256][4];
  __shared__ float sfin[6][4];
  int tid = threadIdx.x;
  for (int si = 0; si < 6; ++si) {
    float a[4] = {0.f, 0.f, 0.f, 0.f};
    for (int i = 0; i < 16; ++i) {
      const float* p = part + ((size_t)si * 4096 + tid + 256 * i) * 4;
      for (int k = 0; k < 4; ++k) a[k] += p[k];
    }
    for (int k = 0; k < 4; ++k) red[tid][k] = a[k];
    __syncthreads();
    for (int st = 128; st >= 1; st >>= 1) {
      if (tid < st) for (int k = 0; k < 4; ++k) red[tid][k] += red[tid + st][k];
      __syncthreads();
    }
    if (tid == 0) for (int k = 0; k < 4; ++k) sfin[si][k] = red[0][k];
    __syncthreads();
  }
  if (tid == 0) {
    gs[0] = 0.f; gs[1] = 1.f; gs[2] = 0.f;
    for (int si = 0; si < 6; ++si) {
      float s[4] = {sfin[si][0], sfin[si][1], sfin[si][2], sfin[si][3]};
      int idx = 0; float best = s[0];
      for (int k = 1; k < 4; ++k) if (s[k] > best) { best = s[k]; idx = k; }
      float second = -3.4e38f;
      for (int k = 0; k < 4; ++k) if (k != idx) second = fmaxf(second, s[k]);
      gs[3 + si] = (float)idx;
      margins[si] = best - second;
    }
  }
}

extern "C" void kernel_launch(void* const* d_in, const int* in_sizes, int n_in,
                              void* d_out, int out_size, void* d_ws, size_t ws_size,
                              hipStream_t stream) {
  const float* x    = (const float*)d_in[0];
  const float* h    = (const float*)d_in[1];
  const float* L    = (const float*)d_in[2];
  const float* R    = (const float*)d_in[3];
  const float* bias = (const float*)d_in[4];
  const float* Ws   = (const float*)d_in[5];

  float* out        = (float*)d_out;
  float* out_hnext  = out;                          // 4,194,304
  float* out_gs     = out + 4194304;                // 9
  float* out_gnode  = out + 4194313;                // 16384*9*256
  float* out_marg   = out + 41943049;               // 6

  // workspace layout (bf16 as ushort)
  ushort* P0   = (ushort*)d_ws;                     // B*1024
  ushort* P1   = P0 + (size_t)BATCH * 1024;
  ushort* P2   = P1 + (size_t)BATCH * 1024;
  ushort* x2b  = P2 + (size_t)BATCH * 1024;
  ushort* h2b  = x2b + (size_t)BATCH * HID;
  ushort* z1b  = h2b + (size_t)BATCH * HID;
  ushort* rb   = z1b + (size_t)BATCH * HID;
  ushort* rhb  = rb  + (size_t)BATCH * HID;
  ushort* htb  = rhb + (size_t)BATCH * HID;
  ushort* omzb = htb + (size_t)BATCH * HID;
  ushort* ztb  = omzb + (size_t)BATCH * HID;
  ushort* z2hb = ztb + (size_t)BATCH * HID;
  ushort* Lt   = z2hb + (size_t)BATCH * HID;        // 1024*256
  ushort* Rt   = Lt + 1024 * 256;
  float*  part = (float*)(Rt + 1024 * 256);         // 6*4096*4 floats

  f2b2_kernel<<<8192, 256, 0, stream>>>(x, h, x2b, h2b);
  wt2_kernel<<<2048, 256, 0, stream>>>(L, R, Lt, Rt);

  gemm_kernel<<<1024, 256, 0, stream>>>(x2b, Lt, P0, 1024);   // xL
  gemm_kernel<<<1024, 256, 0, stream>>>(h2b, Lt, P1, 1024);   // hL
  gemm_kernel<<< 512, 256, 0, stream>>>(h2b, Rt, P2, 512);    // hR[0:2]

  sig_kernel<<<4096, 256, 0, stream>>>(P0, P2, bias, out_gnode, z1b, rb);

  gemm_kernel<<<1024, 256, 0, stream>>>(rb, Rt, P2, 1024);    // rR
  mix_kernel<<<4096, 256, 0, stream>>>(P1, P2, bias, Ws, out_gnode + 3 * 256, rhb,
                                       nullptr, part + 0 * 4096 * 4, 0);  // rh
  gemm_kernel<<<1024, 256, 0, stream>>>(rhb, Rt, P2, 1024);   // rhR
  mix_kernel<<<4096, 256, 0, stream>>>(P0, P2, bias, Ws, out_gnode + 4 * 256, htb,
                                       nullptr, part + 1 * 4096 * 4, 0);  // h_tilde
  gemm_kernel<<<1024, 256, 0, stream>>>(z1b, Rt, P0, 1024);   // z1R (xL dead)
  mix_kernel<<<4096, 256, 0, stream>>>(P0, P0, bias, Ws, out_gnode + 5 * 256, omzb,
                                       nullptr, part + 2 * 4096 * 4, 1);  // oneMinusZ1
  mix_kernel<<<4096, 256, 0, stream>>>(P1, P0, bias, Ws, out_gnode + 7 * 256, z2hb,
                                       nullptr, part + 4 * 4096 * 4, 2);  // z2h = hL*z1R
  gemm_kernel<<<1024, 256, 0, stream>>>(htb, Lt, P1, 1024);   // htL (hL dead)
  gemm_kernel<<<1024, 256, 0, stream>>>(omzb, Rt, P2, 1024);  // omzR
  mix_kernel<<<4096, 256, 0, stream>>>(P1, P2, bias, Ws, out_gnode + 6 * 256, ztb,
                                       nullptr, part + 3 * 4096 * 4, 2);  // zh_tilde
  gemm_kernel<<<1024, 256, 0, stream>>>(ztb, Lt, P0, 1024);   // ztL
  gemm_kernel<<<1024, 256, 0, stream>>>(z2hb, Rt, P1, 1024);  // z2hR
  mix_kernel<<<4096, 256, 0, stream>>>(P0, P1, bias, Ws, out_gnode + 8 * 256, nullptr,
                                       out_hnext, part + 5 * 4096 * 4, 0); // h_next
  fin_kernel<<<1, 256, 0, stream>>>(part, out_gs, out_marg);
}